// Round 6
// baseline (125.711 us; speedup 1.0000x reference)
//
#include <hip/hip_runtime.h>
#include <math.h>

#define EPS_COS 1e-16f
#define EPS_NRM 1e-8f

// Problem constants (B,N,M) = (64, 2048, 256)
constexpr int B = 64;
constexpr int N = 2048;
constexpr int M = 256;

constexpr int BLK    = 256;            // threads per block (4 waves)
constexpr int WAVES  = BLK / 64;       // 4
constexpr int CHUNK  = 128;            // rows of one batch per block
constexpr int RPW    = CHUNK / WAVES;  // 32 rows per wave
constexpr int PAIRS  = RPW / 2;        // 16 row-pairs per wave
constexpr int NCHUNK = N / CHUNK;      // 16 chunks per batch -> grid (16,64)

// ---------------------------------------------------------------------------
// Fused kernel: phase1 (round-3 proven structure) + atomic accumulation +
// last-block-per-batch finalize (threadfence reduction pattern).
//
// phase1: single pass over a 128-row chunk of memory. Half-wave row pairs:
// lanes 0-31 = row 2i, lanes 32-63 = row 2i+1; each lane owns 8 columns.
// cos in [-1,1] -> exp(cos) needs no max subtraction.
// tail: atomicAdd partials into outacc[b,:], zacc[b], s1acc[b]; the 16th
// block to finish batch b computes out[b,:] = (outacc + s1*k)/Z.
// ---------------------------------------------------------------------------
__global__ __launch_bounds__(BLK)
void k_fused(const float* __restrict__ mem,
             const float* __restrict__ kk,
             const float* __restrict__ g,
             const float* __restrict__ w_prev,
             const int*   __restrict__ lu_prev,
             float* outacc,            // [B][M] accumulators (zeroed per call)
             float* zacc,              // [B]
             float* s1acc,             // [B]
             unsigned int* cnt,        // [B]  (zeroed per call)
             float* __restrict__ out)  // [B][M]
{
    const int b    = blockIdx.y;
    const int c    = blockIdx.x;
    const int tid  = threadIdx.x;
    const int w    = tid >> 6;       // wave id 0..3
    const int lane = tid & 63;
    const int half = lane >> 5;      // 0: row 2i, 1: row 2i+1
    const int sub  = lane & 31;

    // ---- k fragments (+eps) for this lane's 8 columns, and ||k_e|| ----
    float4 ka = *reinterpret_cast<const float4*>(kk + (size_t)b * M + sub * 4);
    float4 kb = *reinterpret_cast<const float4*>(kk + (size_t)b * M + 128 + sub * 4);
    ka.x += EPS_COS; ka.y += EPS_COS; ka.z += EPS_COS; ka.w += EPS_COS;
    kb.x += EPS_COS; kb.y += EPS_COS; kb.z += EPS_COS; kb.w += EPS_COS;
    float ksq = ka.x*ka.x + ka.y*ka.y + ka.z*ka.z + ka.w*ka.w
              + kb.x*kb.x + kb.y*kb.y + kb.z*kb.z + kb.w*kb.w;
#pragma unroll
    for (int off = 16; off; off >>= 1) ksq += __shfl_xor(ksq, off);
    const float kn = fmaxf(sqrtf(ksq), EPS_NRM);

    const float gb   = g[b];
    const float* wrp = w_prev + (size_t)b * 2 * N + N;   // w_prev[b,1,:]
    const int*   lup = lu_prev + (size_t)b * N;

    const int rowbase = c * CHUNK + w * RPW;
    const float* p = mem + ((size_t)b * N + rowbase + half) * M + sub * 4;

    float4 accA = make_float4(0.f, 0.f, 0.f, 0.f);
    float4 accB = make_float4(0.f, 0.f, 0.f, 0.f);
    float Zp = 0.f, s1p = 0.f;

    auto process = [&](int i, const float4& va, const float4& vb) {
        float a0 = va.x + EPS_COS, a1 = va.y + EPS_COS;
        float a2 = va.z + EPS_COS, a3 = va.w + EPS_COS;
        float b0 = vb.x + EPS_COS, b1 = vb.y + EPS_COS;
        float b2 = vb.z + EPS_COS, b3 = vb.w + EPS_COS;
        float dot = a0*ka.x + a1*ka.y + a2*ka.z + a3*ka.w
                  + b0*kb.x + b1*kb.y + b2*kb.z + b3*kb.w;
        float msq = a0*a0 + a1*a1 + a2*a2 + a3*a3
                  + b0*b0 + b1*b1 + b2*b2 + b3*b3;
#pragma unroll
        for (int off = 16; off; off >>= 1) {
            dot += __shfl_xor(dot, off);
            msq += __shfl_xor(msq, off);
        }
        const int n = rowbase + 2 * i + half;
        const float cosv = dot / (fmaxf(sqrtf(msq), EPS_NRM) * kn);
        const float e  = __expf(cosv);
        const float lu = (float)lup[n];
        const float ww = gb * wrp[n] + (1.f - gb) * lu;
        Zp += e;
        s1p = fmaf(e, ww, s1p);
        const float cw = e * (1.f - lu);
        accA.x = fmaf(cw, va.x, accA.x);
        accA.y = fmaf(cw, va.y, accA.y);
        accA.z = fmaf(cw, va.z, accA.z);
        accA.w = fmaf(cw, va.w, accA.w);
        accB.x = fmaf(cw, vb.x, accB.x);
        accB.y = fmaf(cw, vb.y, accB.y);
        accB.z = fmaf(cw, vb.z, accB.z);
        accB.w = fmaf(cw, vb.w, accB.w);
    };

    // ---- prefetch-2 pipeline over 16 row-pairs (pair stride = 2 rows) ----
    float4 va0 = *reinterpret_cast<const float4*>(p);
    float4 vb0 = *reinterpret_cast<const float4*>(p + 128);
    float4 va1 = *reinterpret_cast<const float4*>(p + 2 * M);
    float4 vb1 = *reinterpret_cast<const float4*>(p + 2 * M + 128);
#pragma unroll 2
    for (int i = 0; i < PAIRS - 2; ++i) {
        float4 va2 = *reinterpret_cast<const float4*>(p + (size_t)(i + 2) * 2 * M);
        float4 vb2 = *reinterpret_cast<const float4*>(p + (size_t)(i + 2) * 2 * M + 128);
        process(i, va0, vb0);
        va0 = va1; vb0 = vb1;
        va1 = va2; vb1 = vb2;
    }
    process(PAIRS - 2, va0, vb0);
    process(PAIRS - 1, va1, vb1);

    // ---- merge half-waves (once per wave) ----
    accA.x += __shfl_xor(accA.x, 32); accA.y += __shfl_xor(accA.y, 32);
    accA.z += __shfl_xor(accA.z, 32); accA.w += __shfl_xor(accA.w, 32);
    accB.x += __shfl_xor(accB.x, 32); accB.y += __shfl_xor(accB.y, 32);
    accB.z += __shfl_xor(accB.z, 32); accB.w += __shfl_xor(accB.w, 32);
    Zp  += __shfl_xor(Zp, 32);
    s1p += __shfl_xor(s1p, 32);

    // ---- block reduce across the 4 waves ----
    __shared__ float sred[WAVES * M];   // 4 KiB
    __shared__ float sZ[WAVES], sS1[WAVES];
    if (half == 0) {
        *reinterpret_cast<float4*>(&sred[w * M + sub * 4])       = accA;
        *reinterpret_cast<float4*>(&sred[w * M + 128 + sub * 4]) = accB;
    }
    if (lane == 0) { sZ[w] = Zp; sS1[w] = s1p; }
    __syncthreads();

    // ---- accumulate this chunk's partials into per-batch accumulators ----
    {
        float r = 0.f;
#pragma unroll
        for (int q = 0; q < WAVES; ++q) r += sred[q * M + tid];
        atomicAdd(&outacc[(size_t)b * M + tid], r);
    }
    if (tid == 0) {
        float z = 0.f, s = 0.f;
#pragma unroll
        for (int q = 0; q < WAVES; ++q) { z += sZ[q]; s += sS1[q]; }
        atomicAdd(&zacc[b], z);
        atomicAdd(&s1acc[b], s);
    }

    // ---- last-block-per-batch finalize (threadfence reduction pattern) ----
    __threadfence();                 // my atomics visible device-wide
    __syncthreads();                 // everyone in this block fenced
    __shared__ unsigned int s_old;
    if (tid == 0) s_old = atomicAdd(&cnt[b], 1u);
    __syncthreads();

    if (s_old == NCHUNK - 1) {
        __threadfence();             // acquire: see all 16 blocks' atomics
        const float z = zacc[b];
        const float s = s1acc[b];
        const float v = outacc[(size_t)b * M + tid];
        out[(size_t)b * M + tid] = (v + s * kk[(size_t)b * M + tid]) / z;
    }
}

// ---------------------------------------------------------------------------
extern "C" void kernel_launch(void* const* d_in, const int* in_sizes, int n_in,
                              void* d_out, int out_size, void* d_ws, size_t ws_size,
                              hipStream_t stream) {
    const float* mem     = (const float*)d_in[0];  // (B,N,M)
    const float* kk      = (const float*)d_in[1];  // (B,M)
    const float* g       = (const float*)d_in[2];  // (B,1)
    // d_in[3] = gamma  -> dead for the returned output
    const float* w_prev  = (const float*)d_in[4];  // (B,2,N)
    const int*   lu_prev = (const int*)  d_in[5];  // (B,N)
    // d_in[6] = n      -> dead for the returned output (sort branch unused)
    float* out = (float*)d_out;                    // (B,M)

    float* outacc      = (float*)d_ws;             // B*M floats (64 KiB)
    float* zacc        = outacc + (size_t)B * M;   // B floats
    float* s1acc       = zacc + B;                 // B floats
    unsigned int* cnt  = (unsigned int*)(s1acc + B); // B uints

    const size_t clear_bytes = ((size_t)B * M + 2 * B) * sizeof(float)
                             + B * sizeof(unsigned int);
    hipMemsetAsync(d_ws, 0, clear_bytes, stream);

    dim3 grid(NCHUNK, B);   // (16, 64) = 1024 blocks
    k_fused<<<grid, BLK, 0, stream>>>(mem, kk, g, w_prev, lu_prev,
                                      outacc, zacc, s1acc, cnt, out);
}

// Round 7
// 28.637 us; speedup vs baseline: 4.3899x; 4.3899x over previous
//
#include <hip/hip_runtime.h>
#include <math.h>

#define EPS_COS 1e-16f
#define EPS_NRM 1e-8f

// Problem constants (B,N,M) = (64, 2048, 256)
constexpr int B = 64;
constexpr int N = 2048;
constexpr int M = 256;

constexpr int BLK    = 256;            // threads per K1 block (4 waves)
constexpr int WAVES  = BLK / 64;       // 4
constexpr int CHUNK  = 64;             // rows of one batch per block
constexpr int RPW    = CHUNK / WAVES;  // 16 rows per wave
constexpr int PAIRS  = RPW / 2;        // 8 row-pairs per wave
constexpr int NCHUNK = N / CHUNK;      // 32 chunks per batch -> grid (32,64)=2048 blocks

// ---------------------------------------------------------------------------
// K1: round-3 phase1, unchanged except CHUNK (64 rows/block -> 2048 blocks,
// 8 blocks/CU at VGPR=40 -> 32 waves/CU). Half-wave row pairs: lanes 0-31 =
// row 2i, lanes 32-63 = row 2i+1; each lane owns 8 columns. cos in [-1,1] ->
// exp(cos) needs no max subtraction.
// ---------------------------------------------------------------------------
__global__ __launch_bounds__(BLK)
void k1_fused(const float* __restrict__ mem,
              const float* __restrict__ kk,
              const float* __restrict__ g,
              const float* __restrict__ w_prev,
              const int*   __restrict__ lu_prev,
              float* __restrict__ pread,
              float* __restrict__ pZ,
              float* __restrict__ pS1)
{
    const int b    = blockIdx.y;
    const int c    = blockIdx.x;
    const int tid  = threadIdx.x;
    const int w    = tid >> 6;       // wave id 0..3
    const int lane = tid & 63;
    const int half = lane >> 5;      // 0: row 2i, 1: row 2i+1
    const int sub  = lane & 31;

    // k fragments (+eps) for this lane's 8 columns, and ||k_e||
    float4 ka = *reinterpret_cast<const float4*>(kk + (size_t)b * M + sub * 4);
    float4 kb = *reinterpret_cast<const float4*>(kk + (size_t)b * M + 128 + sub * 4);
    ka.x += EPS_COS; ka.y += EPS_COS; ka.z += EPS_COS; ka.w += EPS_COS;
    kb.x += EPS_COS; kb.y += EPS_COS; kb.z += EPS_COS; kb.w += EPS_COS;
    float ksq = ka.x*ka.x + ka.y*ka.y + ka.z*ka.z + ka.w*ka.w
              + kb.x*kb.x + kb.y*kb.y + kb.z*kb.z + kb.w*kb.w;
#pragma unroll
    for (int off = 16; off; off >>= 1) ksq += __shfl_xor(ksq, off);
    const float kn = fmaxf(sqrtf(ksq), EPS_NRM);

    const float gb   = g[b];
    const float* wrp = w_prev + (size_t)b * 2 * N + N;   // w_prev[b,1,:]
    const int*   lup = lu_prev + (size_t)b * N;

    const int rowbase = c * CHUNK + w * RPW;
    const float* p = mem + ((size_t)b * N + rowbase + half) * M + sub * 4;

    float4 accA = make_float4(0.f, 0.f, 0.f, 0.f);
    float4 accB = make_float4(0.f, 0.f, 0.f, 0.f);
    float Zp = 0.f, s1p = 0.f;

    auto process = [&](int i, const float4& va, const float4& vb) {
        float a0 = va.x + EPS_COS, a1 = va.y + EPS_COS;
        float a2 = va.z + EPS_COS, a3 = va.w + EPS_COS;
        float b0 = vb.x + EPS_COS, b1 = vb.y + EPS_COS;
        float b2 = vb.z + EPS_COS, b3 = vb.w + EPS_COS;
        float dot = a0*ka.x + a1*ka.y + a2*ka.z + a3*ka.w
                  + b0*kb.x + b1*kb.y + b2*kb.z + b3*kb.w;
        float msq = a0*a0 + a1*a1 + a2*a2 + a3*a3
                  + b0*b0 + b1*b1 + b2*b2 + b3*b3;
#pragma unroll
        for (int off = 16; off; off >>= 1) {
            dot += __shfl_xor(dot, off);
            msq += __shfl_xor(msq, off);
        }
        const int n = rowbase + 2 * i + half;
        const float cosv = dot / (fmaxf(sqrtf(msq), EPS_NRM) * kn);
        const float e  = __expf(cosv);
        const float lu = (float)lup[n];
        const float ww = gb * wrp[n] + (1.f - gb) * lu;
        Zp += e;
        s1p = fmaf(e, ww, s1p);
        const float cw = e * (1.f - lu);   // weight on raw mem row
        accA.x = fmaf(cw, va.x, accA.x);
        accA.y = fmaf(cw, va.y, accA.y);
        accA.z = fmaf(cw, va.z, accA.z);
        accA.w = fmaf(cw, va.w, accA.w);
        accB.x = fmaf(cw, vb.x, accB.x);
        accB.y = fmaf(cw, vb.y, accB.y);
        accB.z = fmaf(cw, vb.z, accB.z);
        accB.w = fmaf(cw, vb.w, accB.w);
    };

    // prefetch-2 pipeline over 8 row-pairs (pair stride = 2 rows)
    float4 va0 = *reinterpret_cast<const float4*>(p);
    float4 vb0 = *reinterpret_cast<const float4*>(p + 128);
    float4 va1 = *reinterpret_cast<const float4*>(p + 2 * M);
    float4 vb1 = *reinterpret_cast<const float4*>(p + 2 * M + 128);
#pragma unroll 2
    for (int i = 0; i < PAIRS - 2; ++i) {
        float4 va2 = *reinterpret_cast<const float4*>(p + (size_t)(i + 2) * 2 * M);
        float4 vb2 = *reinterpret_cast<const float4*>(p + (size_t)(i + 2) * 2 * M + 128);
        process(i, va0, vb0);
        va0 = va1; vb0 = vb1;
        va1 = va2; vb1 = vb2;
    }
    process(PAIRS - 2, va0, vb0);
    process(PAIRS - 1, va1, vb1);

    // merge the two half-waves (once per wave)
    accA.x += __shfl_xor(accA.x, 32); accA.y += __shfl_xor(accA.y, 32);
    accA.z += __shfl_xor(accA.z, 32); accA.w += __shfl_xor(accA.w, 32);
    accB.x += __shfl_xor(accB.x, 32); accB.y += __shfl_xor(accB.y, 32);
    accB.z += __shfl_xor(accB.z, 32); accB.w += __shfl_xor(accB.w, 32);
    Zp  += __shfl_xor(Zp, 32);
    s1p += __shfl_xor(s1p, 32);

    // block reduce across the 4 waves
    __shared__ float sred[WAVES * M];   // 4 KiB
    __shared__ float sZ[WAVES], sS1[WAVES];
    if (half == 0) {
        *reinterpret_cast<float4*>(&sred[w * M + sub * 4])       = accA;
        *reinterpret_cast<float4*>(&sred[w * M + 128 + sub * 4]) = accB;
    }
    if (lane == 0) { sZ[w] = Zp; sS1[w] = s1p; }
    __syncthreads();

    if (tid < M) {
        float r = 0.f;
#pragma unroll
        for (int q = 0; q < WAVES; ++q) r += sred[q * M + tid];
        pread[((size_t)b * NCHUNK + c) * M + tid] = r;
    }
    if (tid == 0) {
        float z = 0.f, s = 0.f;
#pragma unroll
        for (int q = 0; q < WAVES; ++q) { z += sZ[q]; s += sS1[q]; }
        pZ[b * NCHUNK + c]  = z;
        pS1[b * NCHUNK + c] = s;
    }
}

// ---------------------------------------------------------------------------
// K2: out[b,m] = (sum_c pread[b,c,m] + s1[b]*k[b,m]) / Z[b]
// One block (256 threads) per batch.
// ---------------------------------------------------------------------------
__global__ __launch_bounds__(M)
void k2_final(const float* __restrict__ pread,
              const float* __restrict__ pZ,
              const float* __restrict__ pS1,
              const float* __restrict__ kk,
              float* __restrict__ out)
{
    const int b = blockIdx.x;
    const int t = threadIdx.x;
    float z = 0.f, s = 0.f;
#pragma unroll
    for (int q = 0; q < NCHUNK; ++q) {
        z += pZ[b * NCHUNK + q];
        s += pS1[b * NCHUNK + q];
    }
    const float* pr = pread + (size_t)b * NCHUNK * M + t;
    float sum = 0.f;
#pragma unroll
    for (int q = 0; q < NCHUNK; ++q) sum += pr[(size_t)q * M];
    out[(size_t)b * M + t] = (sum + s * kk[(size_t)b * M + t]) / z;
}

// ---------------------------------------------------------------------------
extern "C" void kernel_launch(void* const* d_in, const int* in_sizes, int n_in,
                              void* d_out, int out_size, void* d_ws, size_t ws_size,
                              hipStream_t stream) {
    const float* mem     = (const float*)d_in[0];  // (B,N,M)
    const float* kk      = (const float*)d_in[1];  // (B,M)
    const float* g       = (const float*)d_in[2];  // (B,1)
    // d_in[3] = gamma  -> dead for the returned output
    const float* w_prev  = (const float*)d_in[4];  // (B,2,N)
    const int*   lu_prev = (const int*)  d_in[5];  // (B,N)
    // d_in[6] = n      -> dead for the returned output (sort branch unused)
    float* out = (float*)d_out;                    // (B,M)

    float* pread = (float*)d_ws;                            // B*NCHUNK*M floats (2 MiB)
    float* pZ    = pread + (size_t)B * NCHUNK * M;          // B*NCHUNK
    float* pS1   = pZ + (size_t)B * NCHUNK;                 // B*NCHUNK

    dim3 g1(NCHUNK, B);   // (32, 64) = 2048 blocks
    k1_fused<<<g1, BLK, 0, stream>>>(mem, kk, g, w_prev, lu_prev, pread, pZ, pS1);
    k2_final<<<B, M, 0, stream>>>(pread, pZ, pS1, kk, out);
}